// Round 3
// baseline (762.292 us; speedup 1.0000x reference)
//
#include <hip/hip_runtime.h>
#include <stdint.h>

#define HIDDEN 512
#define NLAYERS 3
#define KNN 8
#define CAP 64
#define EPSV 1e-5f

typedef unsigned long long u64;

// ---------------------------------------------------------------------------
// kNN: one wave (64 lanes) per node. BIT-EXACT replication of the reference's
// fp32 expansion formula as compiled by XLA-CPU/BLAS on x86 (FMA contraction
// over the c-dimension, x-term first):
//   sq   = fma(y, y, rn(x*x))
//   dot  = fma(yn, ym, rn(xn*xm))          (sgemm k-loop: acc=rn(x·x'); acc=fma(y,y',acc))
//   d2   = fl(fl(sq_n + sq_m) - 2*dot)     (2*dot exact)
// Identical formula for sq and dot => d2[n][n] == 0 bit-exactly; cancellation
// can make the closest-pair d2 negative (sorts before self) — handled by
// dropping position 0 whatever it is, matching idx[:, :, 1:].
// Ordering key: sign-folded fp32 bits (monotone incl. negatives) << 12 | index
// -> ascending d2, ties -> lower index (lax.top_k / stable argsort semantics).
// ---------------------------------------------------------------------------
__global__ __launch_bounds__(256) void knn_kernel(const float2* __restrict__ coords,
                                                  int* __restrict__ knn,
                                                  int N, int total_waves) {
  int wave = (blockIdx.x * blockDim.x + threadIdx.x) >> 6;
  int lane = threadIdx.x & 63;
  if (wave >= total_waves) return;
  int b = wave / N;
  const float2* cb = coords + (size_t)b * N;
  float2 cn = cb[wave - b * N];
  float sqn = __fmaf_rn(cn.y, cn.y, __fmul_rn(cn.x, cn.x));

  u64 list[KNN + 1];
#pragma unroll
  for (int j = 0; j <= KNN; ++j) list[j] = ~0ull;

  for (int m = lane; m < N; m += 64) {
    float2 cm = cb[m];
    float sqm = __fmaf_rn(cm.y, cm.y, __fmul_rn(cm.x, cm.x));
    float dot = __fmaf_rn(cn.y, cm.y, __fmul_rn(cn.x, cm.x));
    float s = __fadd_rn(sqn, sqm);
    float d2 = __fsub_rn(s, __fmul_rn(2.0f, dot));
    unsigned ub = __float_as_uint(d2);
    unsigned k32 = (ub & 0x80000000u) ? ~ub : (ub | 0x80000000u);  // monotone
    u64 key = ((u64)k32 << 12) | (u64)(unsigned)m;  // N=4096 fits in 12 bits
    if (key < list[KNN]) {
      u64 cur = key;
#pragma unroll
      for (int j = 0; j <= KNN; ++j) {
        u64 lo = list[j] < cur ? list[j] : cur;
        u64 hi = list[j] < cur ? cur : list[j];
        list[j] = lo;
        cur = hi;
      }
    }
  }

  // 9 rounds: wave-wide min of per-lane heads; owner pops (keys unique).
  for (int r = 0; r <= KNN; ++r) {
    u64 cand = list[0];
    u64 mn = cand;
#pragma unroll
    for (int o = 32; o > 0; o >>= 1) {
      u64 v = __shfl_xor(mn, o, 64);
      mn = v < mn ? v : mn;
    }
    if (cand == mn) {
#pragma unroll
      for (int j = 0; j < KNN; ++j) list[j] = list[j + 1];
      list[KNN] = ~0ull;
    }
    if (r > 0 && lane == 0) knn[(size_t)wave * KNN + (r - 1)] = (int)(mn & 0xFFFull);
  }
}

// ---------------------------------------------------------------------------
// Reverse adjacency (in-edges) via atomics. In-degree bound for 2D kNN ~ 6k.
// ---------------------------------------------------------------------------
__global__ __launch_bounds__(256) void rev_build_kernel(const int* __restrict__ knn,
                                                        int* __restrict__ cnt,
                                                        int* __restrict__ rev,
                                                        int N, int BN) {
  int e = blockIdx.x * blockDim.x + threadIdx.x;
  if (e >= BN * KNN) return;
  int bn = e >> 3;        // source node (global)
  int m = knn[e];         // target node (batch-local)
  int b = bn / N;
  int gm = b * N + m;
  int pos = atomicAdd(&cnt[gm], 1);
  if (pos < CAP) rev[(size_t)gm * CAP + pos] = bn - b * N;
}

// ---------------------------------------------------------------------------
// Aggregation: x_new[n] = sum over (out(n) UNION in(n)) of x[m].
// One 128-thread block per node; each thread owns one float4 column slice.
// ---------------------------------------------------------------------------
__global__ __launch_bounds__(128) void agg_kernel(const float* __restrict__ x,
                                                  const int* __restrict__ knn,
                                                  const int* __restrict__ cnt,
                                                  const int* __restrict__ rev,
                                                  float* __restrict__ agg, int N) {
  int bn = blockIdx.x;
  int b = bn / N;
  int t = threadIdx.x;
  const int* my = knn + (size_t)bn * KNN;
  int nb[KNN];
#pragma unroll
  for (int j = 0; j < KNN; ++j) nb[j] = my[j];
  const float* xb = x + (size_t)b * N * HIDDEN;
  float4 acc = {0.f, 0.f, 0.f, 0.f};
#pragma unroll
  for (int j = 0; j < KNN; ++j) {
    float4 v = ((const float4*)(xb + (size_t)nb[j] * HIDDEN))[t];
    acc.x += v.x; acc.y += v.y; acc.z += v.z; acc.w += v.w;
  }
  int indeg = cnt[bn];
  if (indeg > CAP) indeg = CAP;
  const int* rv = rev + (size_t)bn * CAP;
  for (int i = 0; i < indeg; ++i) {
    int r = rv[i];
    bool dup = false;
#pragma unroll
    for (int j = 0; j < KNN; ++j) dup = dup || (r == nb[j]);
    if (!dup) {
      float4 v = ((const float4*)(xb + (size_t)r * HIDDEN))[t];
      acc.x += v.x; acc.y += v.y; acc.z += v.z; acc.w += v.w;
    }
  }
  ((float4*)(agg + (size_t)bn * HIDDEN))[t] = acc;
}

// ---------------------------------------------------------------------------
// SGEMM C = A @ W + bias.  A: M x 512, W: 512 x 512, both row-major.
// 64x64 tile, K-step 16, 256 threads, 4x4 micro-tile. fp32 baseline.
// ---------------------------------------------------------------------------
__global__ __launch_bounds__(256) void gemm_bias_kernel(const float* __restrict__ A,
                                                        const float* __restrict__ W,
                                                        const float* __restrict__ bias,
                                                        float* __restrict__ C) {
  __shared__ float As[16][64];
  __shared__ float Bs[16][64];
  int tid = threadIdx.x;
  int tx = tid & 15;   // -> n
  int ty = tid >> 4;   // -> m
  int n0 = blockIdx.x * 64;
  int m0 = blockIdx.y * 64;
  float acc[4][4];
#pragma unroll
  for (int i = 0; i < 4; ++i)
#pragma unroll
    for (int j = 0; j < 4; ++j) acc[i][j] = 0.f;

  int ar = tid >> 2;          // 0..63
  int ac = (tid & 3) << 2;    // 0,4,8,12
  int br = tid >> 4;          // 0..15
  int bc = (tid & 15) << 2;   // 0..60

  for (int k0 = 0; k0 < HIDDEN; k0 += 16) {
    float4 va = *(const float4*)(A + (size_t)(m0 + ar) * HIDDEN + k0 + ac);
    float4 vb = *(const float4*)(W + (size_t)(k0 + br) * HIDDEN + n0 + bc);
    As[ac + 0][ar] = va.x;
    As[ac + 1][ar] = va.y;
    As[ac + 2][ar] = va.z;
    As[ac + 3][ar] = va.w;
    *(float4*)&Bs[br][bc] = vb;
    __syncthreads();
#pragma unroll
    for (int k = 0; k < 16; ++k) {
      float a[4], bb[4];
      *(float4*)a = *(const float4*)&As[k][ty << 2];
      *(float4*)bb = *(const float4*)&Bs[k][tx << 2];
#pragma unroll
      for (int i = 0; i < 4; ++i)
#pragma unroll
        for (int j = 0; j < 4; ++j) acc[i][j] = fmaf(a[i], bb[j], acc[i][j]);
    }
    __syncthreads();
  }
  float4 bv = *(const float4*)(bias + n0 + (tx << 2));
#pragma unroll
  for (int i = 0; i < 4; ++i) {
    float4 o;
    o.x = acc[i][0] + bv.x;
    o.y = acc[i][1] + bv.y;
    o.z = acc[i][2] + bv.z;
    o.w = acc[i][3] + bv.w;
    *(float4*)(C + (size_t)(m0 + (ty << 2) + i) * HIDDEN + n0 + (tx << 2)) = o;
  }
}

// ---------------------------------------------------------------------------
// LayerNorm + ReLU + optional residual. One wave per row (512 = 64 lanes x 8).
// ---------------------------------------------------------------------------
__global__ __launch_bounds__(256) void ln_relu_res_kernel(const float* __restrict__ t,
                                                          const float* __restrict__ res,
                                                          const float* __restrict__ g,
                                                          const float* __restrict__ be,
                                                          float* __restrict__ out,
                                                          int addres) {
  int row = (blockIdx.x << 2) + (threadIdx.x >> 6);
  int lane = threadIdx.x & 63;
  const float4* tr = (const float4*)(t + (size_t)row * HIDDEN);
  float4 v0 = tr[lane];
  float4 v1 = tr[lane + 64];
  float s = ((v0.x + v0.y) + (v0.z + v0.w)) + ((v1.x + v1.y) + (v1.z + v1.w));
  float ss = ((v0.x * v0.x + v0.y * v0.y) + (v0.z * v0.z + v0.w * v0.w)) +
             ((v1.x * v1.x + v1.y * v1.y) + (v1.z * v1.z + v1.w * v1.w));
#pragma unroll
  for (int o = 32; o > 0; o >>= 1) {
    s += __shfl_xor(s, o, 64);
    ss += __shfl_xor(ss, o, 64);
  }
  float mu = s * (1.0f / HIDDEN);
  float var = ss * (1.0f / HIDDEN) - mu * mu;
  float inv = rsqrtf(var + EPSV);
  float4 g0 = ((const float4*)g)[lane], g1 = ((const float4*)g)[lane + 64];
  float4 b0 = ((const float4*)be)[lane], b1 = ((const float4*)be)[lane + 64];
  float4 o0, o1;
  o0.x = fmaxf((v0.x - mu) * inv * g0.x + b0.x, 0.f);
  o0.y = fmaxf((v0.y - mu) * inv * g0.y + b0.y, 0.f);
  o0.z = fmaxf((v0.z - mu) * inv * g0.z + b0.z, 0.f);
  o0.w = fmaxf((v0.w - mu) * inv * g0.w + b0.w, 0.f);
  o1.x = fmaxf((v1.x - mu) * inv * g1.x + b1.x, 0.f);
  o1.y = fmaxf((v1.y - mu) * inv * g1.y + b1.y, 0.f);
  o1.z = fmaxf((v1.z - mu) * inv * g1.z + b1.z, 0.f);
  o1.w = fmaxf((v1.w - mu) * inv * g1.w + b1.w, 0.f);
  if (addres) {
    const float4* rr = (const float4*)(res + (size_t)row * HIDDEN);
    float4 r0 = rr[lane], r1 = rr[lane + 64];
    o0.x += r0.x; o0.y += r0.y; o0.z += r0.z; o0.w += r0.w;
    o1.x += r1.x; o1.y += r1.y; o1.z += r1.z; o1.w += r1.w;
  }
  float4* orow = (float4*)(out + (size_t)row * HIDDEN);
  orow[lane] = o0;
  orow[lane + 64] = o1;
}

// ---------------------------------------------------------------------------
extern "C" void kernel_launch(void* const* d_in, const int* in_sizes, int n_in,
                              void* d_out, int out_size, void* d_ws, size_t ws_size,
                              hipStream_t stream) {
  const float* nf = (const float*)d_in[0];       // (B,N,512)
  const float2* coords = (const float2*)d_in[1]; // (B,N,2)
  const float* Wall = (const float*)d_in[2];     // (3,512,512)
  const float* ball = (const float*)d_in[3];     // (3,512)
  const float* gall = (const float*)d_in[4];     // (3,512)
  const float* beall = (const float*)d_in[5];    // (3,512)
  float* out = (float*)d_out;

  int BN = in_sizes[0] / HIDDEN;  // 16384
  int N = 4096;                   // fixed by setup_inputs

  char* ws = (char*)d_ws;
  size_t off = 0;
  auto alloc = [&](size_t bytes) -> void* {
    off = (off + 255) & ~(size_t)255;
    void* p = ws + off;
    off += bytes;
    return p;
  };
  int* knn = (int*)alloc((size_t)BN * KNN * sizeof(int));
  int* cnt = (int*)alloc((size_t)BN * sizeof(int));
  int* rev = (int*)alloc((size_t)BN * CAP * sizeof(int));
  float* agg = (float*)alloc((size_t)BN * HIDDEN * sizeof(float));
  float* tmp = (float*)alloc((size_t)BN * HIDDEN * sizeof(float));

  hipMemsetAsync(cnt, 0, (size_t)BN * sizeof(int), stream);
  knn_kernel<<<BN / 4, 256, 0, stream>>>(coords, knn, N, BN);
  rev_build_kernel<<<(BN * KNN) / 256, 256, 0, stream>>>(knn, cnt, rev, N, BN);

  for (int l = 0; l < NLAYERS; ++l) {
    const float* xin = (l == 0) ? nf : out;
    agg_kernel<<<BN, 128, 0, stream>>>(xin, knn, cnt, rev, agg, N);
    gemm_bias_kernel<<<dim3(HIDDEN / 64, BN / 64), 256, 0, stream>>>(
        agg, Wall + (size_t)l * HIDDEN * HIDDEN, ball + (size_t)l * HIDDEN, tmp);
    ln_relu_res_kernel<<<BN / 4, 256, 0, stream>>>(
        tmp, out, gall + (size_t)l * HIDDEN, beall + (size_t)l * HIDDEN, out, l > 0);
  }
}

// Round 4
// 443.659 us; speedup vs baseline: 1.7182x; 1.7182x over previous
//
#include <hip/hip_runtime.h>
#include <stdint.h>

#define HIDDEN 512
#define NLAYERS 3
#define KNN 8
#define CAP 64
#define EPSV 1e-5f

typedef unsigned long long u64;
typedef __attribute__((ext_vector_type(8))) short short8;   // 8 bf16 = 4 VGPRs
typedef __attribute__((ext_vector_type(4))) float f32x4;    // MFMA acc

__device__ inline unsigned short f2bf(float x) {  // RNE fp32 -> bf16 bits
  union { float f; unsigned u; } v; v.f = x;
  unsigned r = v.u + 0x7FFFu + ((v.u >> 16) & 1u);
  return (unsigned short)(r >> 16);
}

// ---------------------------------------------------------------------------
// kNN: one wave per node. Bit-exact replica of the checker's fp32 expansion
// (FMA-contracted over c, x-term first):
//   sq  = fma(y,y, rn(x*x));  dot = fma(yn,ym, rn(xn*xm))
//   d2  = fl(fl(sq_n + sq_m) - 2*dot)
// Key: sign-folded fp32 bits << 12 | index -> ascending, ties -> lower index.
// r=0 pops self (d2==0 bit-exact, or the rare negative-cancellation pair).
// ---------------------------------------------------------------------------
__global__ __launch_bounds__(256) void knn_kernel(const float2* __restrict__ coords,
                                                  int* __restrict__ knn,
                                                  int N, int total_waves) {
  int wave = (blockIdx.x * blockDim.x + threadIdx.x) >> 6;
  int lane = threadIdx.x & 63;
  if (wave >= total_waves) return;
  int b = wave / N;
  const float2* cb = coords + (size_t)b * N;
  float2 cn = cb[wave - b * N];
  float sqn = __fmaf_rn(cn.y, cn.y, __fmul_rn(cn.x, cn.x));

  u64 list[KNN + 1];
#pragma unroll
  for (int j = 0; j <= KNN; ++j) list[j] = ~0ull;

  for (int m = lane; m < N; m += 64) {
    float2 cm = cb[m];
    float sqm = __fmaf_rn(cm.y, cm.y, __fmul_rn(cm.x, cm.x));
    float dot = __fmaf_rn(cn.y, cm.y, __fmul_rn(cn.x, cm.x));
    float s = __fadd_rn(sqn, sqm);
    float d2 = __fsub_rn(s, __fmul_rn(2.0f, dot));
    unsigned ub = __float_as_uint(d2);
    unsigned k32 = (ub & 0x80000000u) ? ~ub : (ub | 0x80000000u);
    u64 key = ((u64)k32 << 12) | (u64)(unsigned)m;
    if (key < list[KNN]) {
      u64 cur = key;
#pragma unroll
      for (int j = 0; j <= KNN; ++j) {
        u64 lo = list[j] < cur ? list[j] : cur;
        u64 hi = list[j] < cur ? cur : list[j];
        list[j] = lo;
        cur = hi;
      }
    }
  }

  for (int r = 0; r <= KNN; ++r) {
    u64 cand = list[0];
    u64 mn = cand;
#pragma unroll
    for (int o = 32; o > 0; o >>= 1) {
      u64 v = __shfl_xor(mn, o, 64);
      mn = v < mn ? v : mn;
    }
    if (cand == mn) {
#pragma unroll
      for (int j = 0; j < KNN; ++j) list[j] = list[j + 1];
      list[KNN] = ~0ull;
    }
    if (r > 0 && lane == 0) knn[(size_t)wave * KNN + (r - 1)] = (int)(mn & 0xFFFull);
  }
}

// ---------------------------------------------------------------------------
__global__ __launch_bounds__(256) void rev_build_kernel(const int* __restrict__ knn,
                                                        int* __restrict__ cnt,
                                                        int* __restrict__ rev,
                                                        int N, int BN) {
  int e = blockIdx.x * blockDim.x + threadIdx.x;
  if (e >= BN * KNN) return;
  int bn = e >> 3;
  int m = knn[e];
  int b = bn / N;
  int gm = b * N + m;
  int pos = atomicAdd(&cnt[gm], 1);
  if (pos < CAP) rev[(size_t)gm * CAP + pos] = bn - b * N;
}

// ---------------------------------------------------------------------------
// Aggregation: fp32 gather+sum, bf16 output (feeds the MFMA GEMM).
// ---------------------------------------------------------------------------
__global__ __launch_bounds__(128) void agg_kernel(const float* __restrict__ x,
                                                  const int* __restrict__ knn,
                                                  const int* __restrict__ cnt,
                                                  const int* __restrict__ rev,
                                                  unsigned short* __restrict__ aggb,
                                                  int N) {
  int bn = blockIdx.x;
  int b = bn / N;
  int t = threadIdx.x;
  const int* my = knn + (size_t)bn * KNN;
  int nb[KNN];
#pragma unroll
  for (int j = 0; j < KNN; ++j) nb[j] = my[j];
  const float* xb = x + (size_t)b * N * HIDDEN;
  float4 acc = {0.f, 0.f, 0.f, 0.f};
#pragma unroll
  for (int j = 0; j < KNN; ++j) {
    float4 v = ((const float4*)(xb + (size_t)nb[j] * HIDDEN))[t];
    acc.x += v.x; acc.y += v.y; acc.z += v.z; acc.w += v.w;
  }
  int indeg = cnt[bn];
  if (indeg > CAP) indeg = CAP;
  const int* rv = rev + (size_t)bn * CAP;
  for (int i = 0; i < indeg; ++i) {
    int r = rv[i];
    bool dup = false;
#pragma unroll
    for (int j = 0; j < KNN; ++j) dup = dup || (r == nb[j]);
    if (!dup) {
      float4 v = ((const float4*)(xb + (size_t)r * HIDDEN))[t];
      acc.x += v.x; acc.y += v.y; acc.z += v.z; acc.w += v.w;
    }
  }
  ushort4 o;
  o.x = f2bf(acc.x); o.y = f2bf(acc.y); o.z = f2bf(acc.z); o.w = f2bf(acc.w);
  ((ushort4*)(aggb + (size_t)bn * HIDDEN))[t] = o;
}

// ---------------------------------------------------------------------------
// W convert+transpose: W[l][k][n] fp32 -> Wt[l][n][k] bf16. 64x64 tiles.
// ---------------------------------------------------------------------------
__global__ __launch_bounds__(256) void wconv_kernel(const float* __restrict__ W,
                                                    unsigned short* __restrict__ Wt) {
  __shared__ unsigned short tile[64][65];
  int l = blockIdx.x >> 6;
  int t6 = blockIdx.x & 63;
  int k0 = (t6 >> 3) * 64, n0 = (t6 & 7) * 64;
  const float* Wl = W + (size_t)l * HIDDEN * HIDDEN;
  unsigned short* Wtl = Wt + (size_t)l * HIDDEN * HIDDEN;
  int t = threadIdx.x;
#pragma unroll
  for (int r = 0; r < 4; ++r) {
    int row = (t >> 4) + r * 16;   // k-local
    int col = (t & 15) * 4;        // n-local
    float4 v = *(const float4*)(Wl + (size_t)(k0 + row) * HIDDEN + n0 + col);
    tile[col + 0][row] = f2bf(v.x);
    tile[col + 1][row] = f2bf(v.y);
    tile[col + 2][row] = f2bf(v.z);
    tile[col + 3][row] = f2bf(v.w);
  }
  __syncthreads();
#pragma unroll
  for (int r = 0; r < 4; ++r) {
    int row = (t >> 4) + r * 16;   // n-local
    int col = (t & 15) * 4;        // k-local
    ushort4 o;
    o.x = tile[row][col + 0]; o.y = tile[row][col + 1];
    o.z = tile[row][col + 2]; o.w = tile[row][col + 3];
    *(ushort4*)(Wtl + (size_t)(n0 + row) * HIDDEN + k0 + col) = o;
  }
}

// ---------------------------------------------------------------------------
// bf16 MFMA GEMM: C = A(bf16, Mx512) @ W + bias, W given as Wt[n][k] bf16.
// 128x128 tile, BK=32, 256 threads = 4 waves (2x2), 4x4 MFMA 16x16x32/wave.
// LDS rows padded to 40 bf16 (20 banks -> worst 2-way conflict = free).
// A-frag: A[m=lane&15][k=(lane>>4)*8+j]; B-frag symmetric from Wt[n][k];
// C/D: col=lane&15, row=(lane>>4)*4+reg.
// ---------------------------------------------------------------------------
__global__ __launch_bounds__(256) void gemm_mfma_kernel(
    const unsigned short* __restrict__ A,
    const unsigned short* __restrict__ Wt,
    const float* __restrict__ bias,
    float* __restrict__ C) {
  __shared__ unsigned short As[128 * 40];
  __shared__ unsigned short Bs[128 * 40];
  int t = threadIdx.x;
  int n0 = blockIdx.x * 128;
  int m0 = blockIdx.y * 128;
  int w = t >> 6, lane = t & 63;
  int wr = w >> 1, wc = w & 1;
  int lm = lane & 15, q = lane >> 4;

  f32x4 acc[4][4];
#pragma unroll
  for (int i = 0; i < 4; ++i)
#pragma unroll
    for (int j = 0; j < 4; ++j) acc[i][j] = (f32x4){0.f, 0.f, 0.f, 0.f};

  int srow = t >> 2;          // 0..63
  int scol = (t & 3) * 8;     // 0,8,16,24

  for (int k0 = 0; k0 < HIDDEN; k0 += 32) {
    uint4 a0 = *(const uint4*)(A + (size_t)(m0 + srow) * HIDDEN + k0 + scol);
    uint4 a1 = *(const uint4*)(A + (size_t)(m0 + srow + 64) * HIDDEN + k0 + scol);
    uint4 b0 = *(const uint4*)(Wt + (size_t)(n0 + srow) * HIDDEN + k0 + scol);
    uint4 b1 = *(const uint4*)(Wt + (size_t)(n0 + srow + 64) * HIDDEN + k0 + scol);
    __syncthreads();  // prior-iter LDS reads done before overwrite
    *(uint4*)(As + srow * 40 + scol) = a0;
    *(uint4*)(As + (srow + 64) * 40 + scol) = a1;
    *(uint4*)(Bs + srow * 40 + scol) = b0;
    *(uint4*)(Bs + (srow + 64) * 40 + scol) = b1;
    __syncthreads();
    short8 af[4], bfr[4];
#pragma unroll
    for (int i = 0; i < 4; ++i)
      af[i] = *(const short8*)(As + (wr * 64 + i * 16 + lm) * 40 + q * 8);
#pragma unroll
    for (int j = 0; j < 4; ++j)
      bfr[j] = *(const short8*)(Bs + (wc * 64 + j * 16 + lm) * 40 + q * 8);
#pragma unroll
    for (int i = 0; i < 4; ++i)
#pragma unroll
      for (int j = 0; j < 4; ++j)
        acc[i][j] = __builtin_amdgcn_mfma_f32_16x16x32_bf16(af[i], bfr[j], acc[i][j], 0, 0, 0);
  }

#pragma unroll
  for (int i = 0; i < 4; ++i) {
    int row = m0 + wr * 64 + i * 16 + q * 4;
#pragma unroll
    for (int j = 0; j < 4; ++j) {
      int col = n0 + wc * 64 + j * 16 + lm;
      float bv = bias[col];
#pragma unroll
      for (int r = 0; r < 4; ++r)
        C[(size_t)(row + r) * HIDDEN + col] = acc[i][j][r] + bv;
    }
  }
}

// ---------------------------------------------------------------------------
// LayerNorm + ReLU + optional residual. One wave per row.
// ---------------------------------------------------------------------------
__global__ __launch_bounds__(256) void ln_relu_res_kernel(const float* __restrict__ t,
                                                          const float* __restrict__ res,
                                                          const float* __restrict__ g,
                                                          const float* __restrict__ be,
                                                          float* __restrict__ out,
                                                          int addres) {
  int row = (blockIdx.x << 2) + (threadIdx.x >> 6);
  int lane = threadIdx.x & 63;
  const float4* tr = (const float4*)(t + (size_t)row * HIDDEN);
  float4 v0 = tr[lane];
  float4 v1 = tr[lane + 64];
  float s = ((v0.x + v0.y) + (v0.z + v0.w)) + ((v1.x + v1.y) + (v1.z + v1.w));
  float ss = ((v0.x * v0.x + v0.y * v0.y) + (v0.z * v0.z + v0.w * v0.w)) +
             ((v1.x * v1.x + v1.y * v1.y) + (v1.z * v1.z + v1.w * v1.w));
#pragma unroll
  for (int o = 32; o > 0; o >>= 1) {
    s += __shfl_xor(s, o, 64);
    ss += __shfl_xor(ss, o, 64);
  }
  float mu = s * (1.0f / HIDDEN);
  float var = ss * (1.0f / HIDDEN) - mu * mu;
  float inv = rsqrtf(var + EPSV);
  float4 g0 = ((const float4*)g)[lane], g1 = ((const float4*)g)[lane + 64];
  float4 b0 = ((const float4*)be)[lane], b1 = ((const float4*)be)[lane + 64];
  float4 o0, o1;
  o0.x = fmaxf((v0.x - mu) * inv * g0.x + b0.x, 0.f);
  o0.y = fmaxf((v0.y - mu) * inv * g0.y + b0.y, 0.f);
  o0.z = fmaxf((v0.z - mu) * inv * g0.z + b0.z, 0.f);
  o0.w = fmaxf((v0.w - mu) * inv * g0.w + b0.w, 0.f);
  o1.x = fmaxf((v1.x - mu) * inv * g1.x + b1.x, 0.f);
  o1.y = fmaxf((v1.y - mu) * inv * g1.y + b1.y, 0.f);
  o1.z = fmaxf((v1.z - mu) * inv * g1.z + b1.z, 0.f);
  o1.w = fmaxf((v1.w - mu) * inv * g1.w + b1.w, 0.f);
  if (addres) {
    const float4* rr = (const float4*)(res + (size_t)row * HIDDEN);
    float4 r0 = rr[lane], r1 = rr[lane + 64];
    o0.x += r0.x; o0.y += r0.y; o0.z += r0.z; o0.w += r0.w;
    o1.x += r1.x; o1.y += r1.y; o1.z += r1.z; o1.w += r1.w;
  }
  float4* orow = (float4*)(out + (size_t)row * HIDDEN);
  orow[lane] = o0;
  orow[lane + 64] = o1;
}

// ---------------------------------------------------------------------------
extern "C" void kernel_launch(void* const* d_in, const int* in_sizes, int n_in,
                              void* d_out, int out_size, void* d_ws, size_t ws_size,
                              hipStream_t stream) {
  const float* nf = (const float*)d_in[0];
  const float2* coords = (const float2*)d_in[1];
  const float* Wall = (const float*)d_in[2];
  const float* ball = (const float*)d_in[3];
  const float* gall = (const float*)d_in[4];
  const float* beall = (const float*)d_in[5];
  float* out = (float*)d_out;

  int BN = in_sizes[0] / HIDDEN;  // 16384
  int N = 4096;

  char* ws = (char*)d_ws;
  size_t off = 0;
  auto alloc = [&](size_t bytes) -> void* {
    off = (off + 255) & ~(size_t)255;
    void* p = ws + off;
    off += bytes;
    return p;
  };
  int* knn = (int*)alloc((size_t)BN * KNN * sizeof(int));
  int* cnt = (int*)alloc((size_t)BN * sizeof(int));
  int* rev = (int*)alloc((size_t)BN * CAP * sizeof(int));
  unsigned short* aggb = (unsigned short*)alloc((size_t)BN * HIDDEN * sizeof(unsigned short));
  float* tmp = (float*)alloc((size_t)BN * HIDDEN * sizeof(float));
  unsigned short* Wt = (unsigned short*)alloc((size_t)NLAYERS * HIDDEN * HIDDEN * sizeof(unsigned short));

  hipMemsetAsync(cnt, 0, (size_t)BN * sizeof(int), stream);
  knn_kernel<<<BN / 4, 256, 0, stream>>>(coords, knn, N, BN);
  rev_build_kernel<<<(BN * KNN) / 256, 256, 0, stream>>>(knn, cnt, rev, N, BN);
  wconv_kernel<<<NLAYERS * 64, 256, 0, stream>>>(Wall, Wt);

  for (int l = 0; l < NLAYERS; ++l) {
    const float* xin = (l == 0) ? nf : out;
    agg_kernel<<<BN, 128, 0, stream>>>(xin, knn, cnt, rev, aggb, N);
    gemm_mfma_kernel<<<dim3(HIDDEN / 128, BN / 128), 256, 0, stream>>>(
        aggb, Wt + (size_t)l * HIDDEN * HIDDEN, ball + (size_t)l * HIDDEN, tmp);
    ln_relu_res_kernel<<<BN / 4, 256, 0, stream>>>(
        tmp, out, gall + (size_t)l * HIDDEN, beall + (size_t)l * HIDDEN, out, l > 0);
  }
}

// Round 5
// 345.684 us; speedup vs baseline: 2.2052x; 1.2834x over previous
//
#include <hip/hip_runtime.h>
#include <stdint.h>

#define HIDDEN 512
#define NLAYERS 3
#define KNN 8
#define CAP 64
#define EPSV 1e-5f
#define GRID 32
#define NCELL (GRID * GRID)

typedef unsigned long long u64;
typedef __attribute__((ext_vector_type(8))) short short8;   // 8 bf16 = 4 VGPRs
typedef __attribute__((ext_vector_type(4))) float f32x4;    // MFMA acc

__device__ inline unsigned short f2bf(float x) {  // RNE fp32 -> bf16 bits
  union { float f; unsigned u; } v; v.f = x;
  unsigned r = v.u + 0x7FFFu + ((v.u >> 16) & 1u);
  return (unsigned short)(r >> 16);
}
__device__ inline float bf2f(unsigned short u) {
  return __uint_as_float((unsigned)u << 16);
}

// ---------------------------------------------------------------------------
// Grid build: one 1024-thread block per batch. Counting sort of the batch's
// 4096 points into 32x32 cells: LDS histogram -> LDS Hillis-Steele scan ->
// scatter (order within a cell is irrelevant: top-9 selection is
// scan-order-independent).
// ---------------------------------------------------------------------------
__global__ __launch_bounds__(1024) void grid_build_kernel(
    const float2* __restrict__ coords, int* __restrict__ cell_start,
    float2* __restrict__ scoord, int* __restrict__ sorig, int N) {
  __shared__ int hist[NCELL];
  __shared__ int offs[NCELL];
  int b = blockIdx.x;
  int t = threadIdx.x;
  hist[t] = 0;
  __syncthreads();
  const float2* cb = coords + (size_t)b * N;
  int mycell[4];
#pragma unroll
  for (int r = 0; r < 4; ++r) {
    int i = t + r * 1024;
    float2 c = cb[i];
    int cx = (int)(c.x * GRID); cx = cx < 0 ? 0 : (cx > GRID - 1 ? GRID - 1 : cx);
    int cy = (int)(c.y * GRID); cy = cy < 0 ? 0 : (cy > GRID - 1 ? GRID - 1 : cy);
    mycell[r] = cy * GRID + cx;
    atomicAdd(&hist[mycell[r]], 1);
  }
  __syncthreads();
  int v = hist[t];
  offs[t] = v;
  __syncthreads();
  for (int d = 1; d < NCELL; d <<= 1) {
    int add = (t >= d) ? offs[t - d] : 0;
    __syncthreads();
    offs[t] += add;
    __syncthreads();
  }
  int excl = offs[t] - v;  // exclusive scan
  cell_start[(size_t)b * (NCELL + 1) + t] = excl;
  if (t == 0) cell_start[(size_t)b * (NCELL + 1) + NCELL] = N;
  hist[t] = excl;  // reuse as running write cursor
  __syncthreads();
#pragma unroll
  for (int r = 0; r < 4; ++r) {
    int i = t + r * 1024;
    int pos = atomicAdd(&hist[mycell[r]], 1);
    scoord[(size_t)b * N + pos] = cb[i];
    sorig[(size_t)b * N + pos] = i;
  }
}

// ---------------------------------------------------------------------------
// Grid kNN: one thread per node, expanding Chebyshev rings. Candidate keys use
// the checker's bit-exact fp32 expansion (FMA-contracted, x-first):
//   sq = fma(y,y,rn(x*x)); dot = fma(yn,ym,rn(xn*xm));
//   d2 = fl(fl(sq_n+sq_m) - 2*dot)
// key = signfold(d2)<<12 | idx (ascending d2, ties -> lower index).
// Stop when (q*h)^2 > d2[8th] + 1e-5 (margin >> 1.2e-7 formula noise), so the
// examined set provably contains the checker's top-9. Emit list[1..8]
// (drop global min = self, or the rare negative-cancellation pair), identical
// semantics to idx[:, :, 1:].
// ---------------------------------------------------------------------------
__global__ __launch_bounds__(256) void knn_grid_kernel(
    const float2* __restrict__ coords, const int* __restrict__ cell_start,
    const float2* __restrict__ scoord, const int* __restrict__ sorig,
    int* __restrict__ knn, int N, int BN) {
  int g = blockIdx.x * blockDim.x + threadIdx.x;
  if (g >= BN) return;
  int b = g / N;
  int i = g - b * N;
  float2 cn = coords[(size_t)b * N + i];
  float sqn = __fmaf_rn(cn.y, cn.y, __fmul_rn(cn.x, cn.x));
  int cx = (int)(cn.x * GRID); cx = cx < 0 ? 0 : (cx > GRID - 1 ? GRID - 1 : cx);
  int cy = (int)(cn.y * GRID); cy = cy < 0 ? 0 : (cy > GRID - 1 ? GRID - 1 : cy);
  const int* cs = cell_start + (size_t)b * (NCELL + 1);
  const float2* sc = scoord + (size_t)b * N;
  const int* so = sorig + (size_t)b * N;

  u64 list[KNN + 1];
#pragma unroll
  for (int j = 0; j <= KNN; ++j) list[j] = ~0ull;

  auto scan_cell = [&](int ux, int uy) {
    int c = uy * GRID + ux;
    int s = cs[c], e = cs[c + 1];
    for (int p = s; p < e; ++p) {
      float2 cm = sc[p];
      float sqm = __fmaf_rn(cm.y, cm.y, __fmul_rn(cm.x, cm.x));
      float dot = __fmaf_rn(cn.y, cm.y, __fmul_rn(cn.x, cm.x));
      float d2 = __fsub_rn(__fadd_rn(sqn, sqm), __fmul_rn(2.0f, dot));
      unsigned ub = __float_as_uint(d2);
      unsigned k32 = (ub & 0x80000000u) ? ~ub : (ub | 0x80000000u);
      u64 key = ((u64)k32 << 12) | (u64)(unsigned)so[p];
      if (key < list[KNN]) {
        u64 cur = key;
#pragma unroll
        for (int j = 0; j <= KNN; ++j) {
          u64 lo = list[j] < cur ? list[j] : cur;
          u64 hi = list[j] < cur ? cur : list[j];
          list[j] = lo;
          cur = hi;
        }
      }
    }
  };

  for (int q = 0; q <= GRID; ++q) {
    if (q == 0) {
      scan_cell(cx, cy);
    } else {
      int x0 = cx - q, x1 = cx + q, y0 = cy - q, y1 = cy + q;
      int xa = x0 < 0 ? 0 : x0, xb_ = x1 > GRID - 1 ? GRID - 1 : x1;
      for (int ux = xa; ux <= xb_; ++ux) {
        if (y0 >= 0) scan_cell(ux, y0);
        if (y1 <= GRID - 1) scan_cell(ux, y1);
      }
      int ya = (y0 + 1) < 0 ? 0 : y0 + 1, yb = (y1 - 1) > GRID - 1 ? GRID - 1 : y1 - 1;
      for (int uy = ya; uy <= yb; ++uy) {
        if (x0 >= 0) scan_cell(x0, uy);
        if (x1 <= GRID - 1) scan_cell(x1, uy);
      }
    }
    if (list[KNN] != ~0ull) {
      unsigned k32 = (unsigned)(list[KNN] >> 12);
      float d2w = (k32 >= 0x80000000u) ? __uint_as_float(k32 ^ 0x80000000u) : 0.0f;
      float bound = (float)q * (1.0f / GRID);
      if (bound * bound > d2w + 1e-5f) break;
    }
  }
#pragma unroll
  for (int j = 0; j < KNN; ++j)
    knn[(size_t)g * KNN + j] = (int)(list[j + 1] & 0xFFFull);
}

// ---------------------------------------------------------------------------
__global__ __launch_bounds__(256) void rev_build_kernel(const int* __restrict__ knn,
                                                        int* __restrict__ cnt,
                                                        int* __restrict__ rev,
                                                        int N, int BN) {
  int e = blockIdx.x * blockDim.x + threadIdx.x;
  if (e >= BN * KNN) return;
  int bn = e >> 3;
  int m = knn[e];
  int b = bn / N;
  int gm = b * N + m;
  int pos = atomicAdd(&cnt[gm], 1);
  if (pos < CAP) rev[(size_t)gm * CAP + pos] = bn - b * N;
}

// ---------------------------------------------------------------------------
// fp32 -> bf16 bulk convert (layer-0 agg input).
// ---------------------------------------------------------------------------
__global__ __launch_bounds__(256) void x2bf_kernel(const float* __restrict__ x,
                                                   unsigned short* __restrict__ xb,
                                                   int n4) {
  int i = blockIdx.x * blockDim.x + threadIdx.x;
  if (i >= n4) return;
  float4 v = ((const float4*)x)[i];
  ushort4 o;
  o.x = f2bf(v.x); o.y = f2bf(v.y); o.z = f2bf(v.z); o.w = f2bf(v.w);
  ((ushort4*)xb)[i] = o;
}

// ---------------------------------------------------------------------------
// Aggregation: gather bf16 rows, fp32 accumulate, bf16 out (feeds MFMA GEMM).
// ---------------------------------------------------------------------------
__global__ __launch_bounds__(128) void agg_kernel(const unsigned short* __restrict__ x,
                                                  const int* __restrict__ knn,
                                                  const int* __restrict__ cnt,
                                                  const int* __restrict__ rev,
                                                  unsigned short* __restrict__ aggb,
                                                  int N) {
  int bn = blockIdx.x;
  int b = bn / N;
  int t = threadIdx.x;
  const int* my = knn + (size_t)bn * KNN;
  int nb[KNN];
#pragma unroll
  for (int j = 0; j < KNN; ++j) nb[j] = my[j];
  const unsigned short* xb = x + (size_t)b * N * HIDDEN;
  float4 acc = {0.f, 0.f, 0.f, 0.f};
#pragma unroll
  for (int j = 0; j < KNN; ++j) {
    ushort4 v = ((const ushort4*)(xb + (size_t)nb[j] * HIDDEN))[t];
    acc.x += bf2f(v.x); acc.y += bf2f(v.y); acc.z += bf2f(v.z); acc.w += bf2f(v.w);
  }
  int indeg = cnt[bn];
  if (indeg > CAP) indeg = CAP;
  const int* rv = rev + (size_t)bn * CAP;
  for (int i = 0; i < indeg; ++i) {
    int r = rv[i];
    bool dup = false;
#pragma unroll
    for (int j = 0; j < KNN; ++j) dup = dup || (r == nb[j]);
    if (!dup) {
      ushort4 v = ((const ushort4*)(xb + (size_t)r * HIDDEN))[t];
      acc.x += bf2f(v.x); acc.y += bf2f(v.y); acc.z += bf2f(v.z); acc.w += bf2f(v.w);
    }
  }
  ushort4 o;
  o.x = f2bf(acc.x); o.y = f2bf(acc.y); o.z = f2bf(acc.z); o.w = f2bf(acc.w);
  ((ushort4*)(aggb + (size_t)bn * HIDDEN))[t] = o;
}

// ---------------------------------------------------------------------------
// W convert+transpose: W[l][k][n] fp32 -> Wt[l][n][k] bf16. 64x64 tiles.
// ---------------------------------------------------------------------------
__global__ __launch_bounds__(256) void wconv_kernel(const float* __restrict__ W,
                                                    unsigned short* __restrict__ Wt) {
  __shared__ unsigned short tile[64][65];
  int l = blockIdx.x >> 6;
  int t6 = blockIdx.x & 63;
  int k0 = (t6 >> 3) * 64, n0 = (t6 & 7) * 64;
  const float* Wl = W + (size_t)l * HIDDEN * HIDDEN;
  unsigned short* Wtl = Wt + (size_t)l * HIDDEN * HIDDEN;
  int t = threadIdx.x;
#pragma unroll
  for (int r = 0; r < 4; ++r) {
    int row = (t >> 4) + r * 16;
    int col = (t & 15) * 4;
    float4 v = *(const float4*)(Wl + (size_t)(k0 + row) * HIDDEN + n0 + col);
    tile[col + 0][row] = f2bf(v.x);
    tile[col + 1][row] = f2bf(v.y);
    tile[col + 2][row] = f2bf(v.z);
    tile[col + 3][row] = f2bf(v.w);
  }
  __syncthreads();
#pragma unroll
  for (int r = 0; r < 4; ++r) {
    int row = (t >> 4) + r * 16;
    int col = (t & 15) * 4;
    ushort4 o;
    o.x = tile[row][col + 0]; o.y = tile[row][col + 1];
    o.z = tile[row][col + 2]; o.w = tile[row][col + 3];
    *(ushort4*)(Wtl + (size_t)(n0 + row) * HIDDEN + k0 + col) = o;
  }
}

// ---------------------------------------------------------------------------
// bf16 MFMA GEMM: C = A(bf16, Mx512) @ W + bias, W given as Wt[n][k] bf16.
// 128x128 tile, BK=32, 4 waves (2x2), 4x4 MFMA 16x16x32/wave. Rows padded to
// 40 bf16 (20 banks -> worst 2-way conflict = free). C/D: col=lane&15,
// row=(lane>>4)*4+reg; A-frag A[m=lane&15][k=(lane>>4)*8+j]; B symmetric.
// ---------------------------------------------------------------------------
__global__ __launch_bounds__(256) void gemm_mfma_kernel(
    const unsigned short* __restrict__ A,
    const unsigned short* __restrict__ Wt,
    const float* __restrict__ bias,
    float* __restrict__ C) {
  __shared__ unsigned short As[128 * 40];
  __shared__ unsigned short Bs[128 * 40];
  int t = threadIdx.x;
  int n0 = blockIdx.x * 128;
  int m0 = blockIdx.y * 128;
  int w = t >> 6, lane = t & 63;
  int wr = w >> 1, wc = w & 1;
  int lm = lane & 15, q = lane >> 4;

  f32x4 acc[4][4];
#pragma unroll
  for (int i = 0; i < 4; ++i)
#pragma unroll
    for (int j = 0; j < 4; ++j) acc[i][j] = (f32x4){0.f, 0.f, 0.f, 0.f};

  int srow = t >> 2;
  int scol = (t & 3) * 8;

  for (int k0 = 0; k0 < HIDDEN; k0 += 32) {
    uint4 a0 = *(const uint4*)(A + (size_t)(m0 + srow) * HIDDEN + k0 + scol);
    uint4 a1 = *(const uint4*)(A + (size_t)(m0 + srow + 64) * HIDDEN + k0 + scol);
    uint4 b0 = *(const uint4*)(Wt + (size_t)(n0 + srow) * HIDDEN + k0 + scol);
    uint4 b1 = *(const uint4*)(Wt + (size_t)(n0 + srow + 64) * HIDDEN + k0 + scol);
    __syncthreads();
    *(uint4*)(As + srow * 40 + scol) = a0;
    *(uint4*)(As + (srow + 64) * 40 + scol) = a1;
    *(uint4*)(Bs + srow * 40 + scol) = b0;
    *(uint4*)(Bs + (srow + 64) * 40 + scol) = b1;
    __syncthreads();
    short8 af[4], bfr[4];
#pragma unroll
    for (int i = 0; i < 4; ++i)
      af[i] = *(const short8*)(As + (wr * 64 + i * 16 + lm) * 40 + q * 8);
#pragma unroll
    for (int j = 0; j < 4; ++j)
      bfr[j] = *(const short8*)(Bs + (wc * 64 + j * 16 + lm) * 40 + q * 8);
#pragma unroll
    for (int i = 0; i < 4; ++i)
#pragma unroll
      for (int j = 0; j < 4; ++j)
        acc[i][j] = __builtin_amdgcn_mfma_f32_16x16x32_bf16(af[i], bfr[j], acc[i][j], 0, 0, 0);
  }

#pragma unroll
  for (int i = 0; i < 4; ++i) {
    int row = m0 + wr * 64 + i * 16 + q * 4;
#pragma unroll
    for (int j = 0; j < 4; ++j) {
      int col = n0 + wc * 64 + j * 16 + lm;
      float bv = bias[col];
#pragma unroll
      for (int r = 0; r < 4; ++r)
        C[(size_t)(row + r) * HIDDEN + col] = acc[i][j][r] + bv;
    }
  }
}

// ---------------------------------------------------------------------------
// LayerNorm + ReLU + residual; writes fp32 out AND bf16 mirror for next agg.
// ---------------------------------------------------------------------------
__global__ __launch_bounds__(256) void ln_relu_res_kernel(const float* __restrict__ t,
                                                          const float* __restrict__ res,
                                                          const float* __restrict__ g,
                                                          const float* __restrict__ be,
                                                          float* __restrict__ out,
                                                          unsigned short* __restrict__ xbout,
                                                          int addres) {
  int row = (blockIdx.x << 2) + (threadIdx.x >> 6);
  int lane = threadIdx.x & 63;
  const float4* tr = (const float4*)(t + (size_t)row * HIDDEN);
  float4 v0 = tr[lane];
  float4 v1 = tr[lane + 64];
  float s = ((v0.x + v0.y) + (v0.z + v0.w)) + ((v1.x + v1.y) + (v1.z + v1.w));
  float ss = ((v0.x * v0.x + v0.y * v0.y) + (v0.z * v0.z + v0.w * v0.w)) +
             ((v1.x * v1.x + v1.y * v1.y) + (v1.z * v1.z + v1.w * v1.w));
#pragma unroll
  for (int o = 32; o > 0; o >>= 1) {
    s += __shfl_xor(s, o, 64);
    ss += __shfl_xor(ss, o, 64);
  }
  float mu = s * (1.0f / HIDDEN);
  float var = ss * (1.0f / HIDDEN) - mu * mu;
  float inv = rsqrtf(var + EPSV);
  float4 g0 = ((const float4*)g)[lane], g1 = ((const float4*)g)[lane + 64];
  float4 b0 = ((const float4*)be)[lane], b1 = ((const float4*)be)[lane + 64];
  float4 o0, o1;
  o0.x = fmaxf((v0.x - mu) * inv * g0.x + b0.x, 0.f);
  o0.y = fmaxf((v0.y - mu) * inv * g0.y + b0.y, 0.f);
  o0.z = fmaxf((v0.z - mu) * inv * g0.z + b0.z, 0.f);
  o0.w = fmaxf((v0.w - mu) * inv * g0.w + b0.w, 0.f);
  o1.x = fmaxf((v1.x - mu) * inv * g1.x + b1.x, 0.f);
  o1.y = fmaxf((v1.y - mu) * inv * g1.y + b1.y, 0.f);
  o1.z = fmaxf((v1.z - mu) * inv * g1.z + b1.z, 0.f);
  o1.w = fmaxf((v1.w - mu) * inv * g1.w + b1.w, 0.f);
  if (addres) {
    const float4* rr = (const float4*)(res + (size_t)row * HIDDEN);
    float4 r0 = rr[lane], r1 = rr[lane + 64];
    o0.x += r0.x; o0.y += r0.y; o0.z += r0.z; o0.w += r0.w;
    o1.x += r1.x; o1.y += r1.y; o1.z += r1.z; o1.w += r1.w;
  }
  float4* orow = (float4*)(out + (size_t)row * HIDDEN);
  orow[lane] = o0;
  orow[lane + 64] = o1;
  ushort4 q0, q1;
  q0.x = f2bf(o0.x); q0.y = f2bf(o0.y); q0.z = f2bf(o0.z); q0.w = f2bf(o0.w);
  q1.x = f2bf(o1.x); q1.y = f2bf(o1.y); q1.z = f2bf(o1.z); q1.w = f2bf(o1.w);
  ushort4* xrow = (ushort4*)(xbout + (size_t)row * HIDDEN);
  xrow[lane] = q0;
  xrow[lane + 64] = q1;
}

// ---------------------------------------------------------------------------
extern "C" void kernel_launch(void* const* d_in, const int* in_sizes, int n_in,
                              void* d_out, int out_size, void* d_ws, size_t ws_size,
                              hipStream_t stream) {
  const float* nf = (const float*)d_in[0];
  const float2* coords = (const float2*)d_in[1];
  const float* Wall = (const float*)d_in[2];
  const float* ball = (const float*)d_in[3];
  const float* gall = (const float*)d_in[4];
  const float* beall = (const float*)d_in[5];
  float* out = (float*)d_out;

  int BN = in_sizes[0] / HIDDEN;  // 16384
  int N = 4096;
  int B = BN / N;

  char* ws = (char*)d_ws;
  size_t off = 0;
  auto alloc = [&](size_t bytes) -> void* {
    off = (off + 255) & ~(size_t)255;
    void* p = ws + off;
    off += bytes;
    return p;
  };
  int* knn = (int*)alloc((size_t)BN * KNN * sizeof(int));
  int* cnt = (int*)alloc((size_t)BN * sizeof(int));
  int* rev = (int*)alloc((size_t)BN * CAP * sizeof(int));
  unsigned short* aggb = (unsigned short*)alloc((size_t)BN * HIDDEN * sizeof(unsigned short));
  float* tmp = (float*)alloc((size_t)BN * HIDDEN * sizeof(float));
  unsigned short* Wt = (unsigned short*)alloc((size_t)NLAYERS * HIDDEN * HIDDEN * sizeof(unsigned short));
  unsigned short* xb = (unsigned short*)alloc((size_t)BN * HIDDEN * sizeof(unsigned short));
  int* cell_start = (int*)alloc((size_t)B * (NCELL + 1) * sizeof(int));
  float2* scoord = (float2*)alloc((size_t)BN * sizeof(float2));
  int* sorig = (int*)alloc((size_t)BN * sizeof(int));

  hipMemsetAsync(cnt, 0, (size_t)BN * sizeof(int), stream);
  grid_build_kernel<<<B, 1024, 0, stream>>>(coords, cell_start, scoord, sorig, N);
  knn_grid_kernel<<<(BN + 255) / 256, 256, 0, stream>>>(coords, cell_start, scoord, sorig, knn, N, BN);
  rev_build_kernel<<<(BN * KNN) / 256, 256, 0, stream>>>(knn, cnt, rev, N, BN);
  wconv_kernel<<<NLAYERS * 64, 256, 0, stream>>>(Wall, Wt);
  x2bf_kernel<<<(BN * HIDDEN / 4 + 255) / 256, 256, 0, stream>>>(nf, xb, BN * HIDDEN / 4);

  for (int l = 0; l < NLAYERS; ++l) {
    agg_kernel<<<BN, 128, 0, stream>>>(xb, knn, cnt, rev, aggb, N);
    gemm_mfma_kernel<<<dim3(HIDDEN / 128, BN / 128), 256, 0, stream>>>(
        aggb, Wt + (size_t)l * HIDDEN * HIDDEN, ball + (size_t)l * HIDDEN, tmp);
    ln_relu_res_kernel<<<BN / 4, 256, 0, stream>>>(
        tmp, out, gall + (size_t)l * HIDDEN, beall + (size_t)l * HIDDEN, out, xb, l > 0);
  }
}

// Round 6
// 296.448 us; speedup vs baseline: 2.5714x; 1.1661x over previous
//
#include <hip/hip_runtime.h>
#include <stdint.h>

#define HIDDEN 512
#define NLAYERS 3
#define KNN 8
#define CAP 64
#define EPSV 1e-5f
#define GRID 32
#define NCELL (GRID * GRID)

typedef unsigned long long u64;
typedef __attribute__((ext_vector_type(8))) short short8;   // 8 bf16 = 4 VGPRs
typedef __attribute__((ext_vector_type(4))) float f32x4;    // MFMA acc

__device__ inline unsigned short f2bf(float x) {  // RNE fp32 -> bf16 bits
  union { float f; unsigned u; } v; v.f = x;
  unsigned r = v.u + 0x7FFFu + ((v.u >> 16) & 1u);
  return (unsigned short)(r >> 16);
}
__device__ inline float bf2f(unsigned short u) {
  return __uint_as_float((unsigned)u << 16);
}

// ---------------------------------------------------------------------------
// Grid build: one 1024-thread block per batch. Counting sort into 32x32 cells.
// Sorted order (scoord/sorig) is ALSO the processing order of the whole
// pipeline this round (spatial locality for agg gathers).
// ---------------------------------------------------------------------------
__global__ __launch_bounds__(1024) void grid_build_kernel(
    const float2* __restrict__ coords, int* __restrict__ cell_start,
    float2* __restrict__ scoord, int* __restrict__ sorig, int N) {
  __shared__ int hist[NCELL];
  __shared__ int offs[NCELL];
  int b = blockIdx.x;
  int t = threadIdx.x;
  hist[t] = 0;
  __syncthreads();
  const float2* cb = coords + (size_t)b * N;
  int mycell[4];
#pragma unroll
  for (int r = 0; r < 4; ++r) {
    int i = t + r * 1024;
    float2 c = cb[i];
    int cx = (int)(c.x * GRID); cx = cx < 0 ? 0 : (cx > GRID - 1 ? GRID - 1 : cx);
    int cy = (int)(c.y * GRID); cy = cy < 0 ? 0 : (cy > GRID - 1 ? GRID - 1 : cy);
    mycell[r] = cy * GRID + cx;
    atomicAdd(&hist[mycell[r]], 1);
  }
  __syncthreads();
  int v = hist[t];
  offs[t] = v;
  __syncthreads();
  for (int d = 1; d < NCELL; d <<= 1) {
    int add = (t >= d) ? offs[t - d] : 0;
    __syncthreads();
    offs[t] += add;
    __syncthreads();
  }
  int excl = offs[t] - v;
  cell_start[(size_t)b * (NCELL + 1) + t] = excl;
  if (t == 0) cell_start[(size_t)b * (NCELL + 1) + NCELL] = N;
  hist[t] = excl;
  __syncthreads();
#pragma unroll
  for (int r = 0; r < 4; ++r) {
    int i = t + r * 1024;
    int pos = atomicAdd(&hist[mycell[r]], 1);
    scoord[(size_t)b * N + pos] = cb[i];
    sorig[(size_t)b * N + pos] = i;
  }
}

// ---------------------------------------------------------------------------
// Gang-of-8 grid kNN. 8 lanes per node (node = sorted position). Lanes scan
// cell candidates strided by 8, each keeping a private top-9 of keys
//   key = signfold(checker-exact d2) << 24 | orig_idx << 12 | sorted_pos
// (tie-break on orig_idx = checker stable-argsort semantics; sorted_pos is
// payload only). Ring stop: gang-count of kept entries with
// d2 < (q*h)^2 - 1e-5  >= 9  ==> checker's top-9 provably scanned (margin
// 1e-5 >> 1.2e-7 expansion-formula noise). Merge: 9 rounds of gang-min
// (3x shfl_xor), owner pops; r=0 drops self/global-min, r=1..8 emit.
// d2 formula bit-exact to checker: sq=fma(y,y,rn(x*x)); dot=fma(yn,ym,
// rn(xn*xm)); d2=fl(fl(sqn+sqm)-2*dot).
// ---------------------------------------------------------------------------
__global__ __launch_bounds__(256) void knn_grid_kernel(
    const int* __restrict__ cell_start, const float2* __restrict__ scoord,
    const int* __restrict__ sorig, int* __restrict__ knn_s, int N, int BN) {
  int gang = (blockIdx.x * blockDim.x + threadIdx.x) >> 3;
  int sub = threadIdx.x & 7;
  if (gang >= BN) return;
  int b = gang / N;
  float2 cn = scoord[gang];
  float sqn = __fmaf_rn(cn.y, cn.y, __fmul_rn(cn.x, cn.x));
  int cx = (int)(cn.x * GRID); cx = cx < 0 ? 0 : (cx > GRID - 1 ? GRID - 1 : cx);
  int cy = (int)(cn.y * GRID); cy = cy < 0 ? 0 : (cy > GRID - 1 ? GRID - 1 : cy);
  const int* cs = cell_start + (size_t)b * (NCELL + 1);
  const float2* sc = scoord + (size_t)b * N;
  const int* so = sorig + (size_t)b * N;

  u64 list[KNN + 1];
#pragma unroll
  for (int j = 0; j <= KNN; ++j) list[j] = ~0ull;

  auto scan_cell = [&](int ux, int uy) {
    int c = uy * GRID + ux;
    int s = cs[c], e = cs[c + 1];
    for (int p = s + sub; p < e; p += 8) {
      float2 cm = sc[p];
      float sqm = __fmaf_rn(cm.y, cm.y, __fmul_rn(cm.x, cm.x));
      float dot = __fmaf_rn(cn.y, cm.y, __fmul_rn(cn.x, cm.x));
      float d2 = __fsub_rn(__fadd_rn(sqn, sqm), __fmul_rn(2.0f, dot));
      unsigned ub = __float_as_uint(d2);
      unsigned k32 = (ub & 0x80000000u) ? ~ub : (ub | 0x80000000u);
      u64 key = ((u64)k32 << 24) | ((u64)(unsigned)so[p] << 12) | (u64)(unsigned)p;
      if (key < list[KNN]) {
        u64 cur = key;
#pragma unroll
        for (int j = 0; j <= KNN; ++j) {
          u64 lo = list[j] < cur ? list[j] : cur;
          u64 hi = list[j] < cur ? cur : list[j];
          list[j] = lo;
          cur = hi;
        }
      }
    }
  };

  for (int q = 0; q <= GRID; ++q) {
    if (q == 0) {
      scan_cell(cx, cy);
    } else {
      int x0 = cx - q, x1 = cx + q, y0 = cy - q, y1 = cy + q;
      int xa = x0 < 0 ? 0 : x0, xb_ = x1 > GRID - 1 ? GRID - 1 : x1;
      for (int ux = xa; ux <= xb_; ++ux) {
        if (y0 >= 0) scan_cell(ux, y0);
        if (y1 <= GRID - 1) scan_cell(ux, y1);
      }
      int ya = (y0 + 1) < 0 ? 0 : y0 + 1, yb = (y1 - 1) > GRID - 1 ? GRID - 1 : y1 - 1;
      for (int uy = ya; uy <= yb; ++uy) {
        if (x0 >= 0) scan_cell(x0, uy);
        if (x1 <= GRID - 1) scan_cell(x1, uy);
      }
      // conservative stop: >=9 kept candidates strictly inside covered radius
      float bound = (float)q * (1.0f / GRID);
      float thr = bound * bound - 1e-5f;
      int cntn = 0;
#pragma unroll
      for (int j = 0; j <= KNN; ++j) {
        unsigned k32 = (unsigned)(list[j] >> 24);
        float d2v = (k32 >= 0x80000000u) ? __uint_as_float(k32 & 0x7FFFFFFFu)
                                         : -__uint_as_float(~k32);
        cntn += (list[j] != ~0ull && d2v < thr) ? 1 : 0;
      }
#pragma unroll
      for (int o = 1; o < 8; o <<= 1) cntn += __shfl_xor(cntn, o, 64);
      if (cntn >= 9) break;
    }
  }

  // merge across the 8 lanes: 9 pops (r=0 = self/global-min, dropped)
  for (int r = 0; r <= KNN; ++r) {
    u64 cand = list[0];
    u64 mn = cand;
#pragma unroll
    for (int o = 1; o < 8; o <<= 1) {
      u64 v = __shfl_xor(mn, o, 64);
      mn = v < mn ? v : mn;
    }
    if (cand == mn) {  // unique owner (keys unique via orig idx)
#pragma unroll
      for (int j = 0; j < KNN; ++j) list[j] = list[j + 1];
      list[KNN] = ~0ull;
      if (r > 0) knn_s[(size_t)gang * KNN + (r - 1)] = (int)(mn & 0xFFFull);
    }
  }
}

// ---------------------------------------------------------------------------
__global__ __launch_bounds__(256) void rev_build_kernel(const int* __restrict__ knn,
                                                        int* __restrict__ cnt,
                                                        int* __restrict__ rev,
                                                        int N, int BN) {
  int e = blockIdx.x * blockDim.x + threadIdx.x;
  if (e >= BN * KNN) return;
  int bn = e >> 3;
  int m = knn[e];
  int b = bn / N;
  int gm = b * N + m;
  int pos = atomicAdd(&cnt[gm], 1);
  if (pos < CAP) rev[(size_t)gm * CAP + pos] = bn - b * N;
}

// ---------------------------------------------------------------------------
// Initial features -> bf16, permuted to sorted order: xs[p] = bf16(nf[orig[p]]).
// ---------------------------------------------------------------------------
__global__ __launch_bounds__(128) void x2bf_perm_kernel(const float* __restrict__ x,
                                                        const int* __restrict__ sorig,
                                                        unsigned short* __restrict__ xs,
                                                        int N) {
  int row = blockIdx.x;
  int b = row / N;
  int src = b * N + sorig[row];
  int t = threadIdx.x;
  float4 v = ((const float4*)(x + (size_t)src * HIDDEN))[t];
  ushort4 o;
  o.x = f2bf(v.x); o.y = f2bf(v.y); o.z = f2bf(v.z); o.w = f2bf(v.w);
  ((ushort4*)(xs + (size_t)row * HIDDEN))[t] = o;
}

// ---------------------------------------------------------------------------
// Aggregation in sorted space: neighbors are spatially (=index-)local -> L2.
// ---------------------------------------------------------------------------
__global__ __launch_bounds__(128) void agg_kernel(const unsigned short* __restrict__ x,
                                                  const int* __restrict__ knn,
                                                  const int* __restrict__ cnt,
                                                  const int* __restrict__ rev,
                                                  unsigned short* __restrict__ aggb,
                                                  int N) {
  int bn = blockIdx.x;
  int b = bn / N;
  int t = threadIdx.x;
  const int* my = knn + (size_t)bn * KNN;
  int nb[KNN];
#pragma unroll
  for (int j = 0; j < KNN; ++j) nb[j] = my[j];
  const unsigned short* xb = x + (size_t)b * N * HIDDEN;
  float4 acc = {0.f, 0.f, 0.f, 0.f};
#pragma unroll
  for (int j = 0; j < KNN; ++j) {
    ushort4 v = ((const ushort4*)(xb + (size_t)nb[j] * HIDDEN))[t];
    acc.x += bf2f(v.x); acc.y += bf2f(v.y); acc.z += bf2f(v.z); acc.w += bf2f(v.w);
  }
  int indeg = cnt[bn];
  if (indeg > CAP) indeg = CAP;
  const int* rv = rev + (size_t)bn * CAP;
  for (int i = 0; i < indeg; ++i) {
    int r = rv[i];
    bool dup = false;
#pragma unroll
    for (int j = 0; j < KNN; ++j) dup = dup || (r == nb[j]);
    if (!dup) {
      ushort4 v = ((const ushort4*)(xb + (size_t)r * HIDDEN))[t];
      acc.x += bf2f(v.x); acc.y += bf2f(v.y); acc.z += bf2f(v.z); acc.w += bf2f(v.w);
    }
  }
  ushort4 o;
  o.x = f2bf(acc.x); o.y = f2bf(acc.y); o.z = f2bf(acc.z); o.w = f2bf(acc.w);
  ((ushort4*)(aggb + (size_t)bn * HIDDEN))[t] = o;
}

// ---------------------------------------------------------------------------
// W convert+transpose: W[l][k][n] fp32 -> Wt[l][n][k] bf16.
// ---------------------------------------------------------------------------
__global__ __launch_bounds__(256) void wconv_kernel(const float* __restrict__ W,
                                                    unsigned short* __restrict__ Wt) {
  __shared__ unsigned short tile[64][65];
  int l = blockIdx.x >> 6;
  int t6 = blockIdx.x & 63;
  int k0 = (t6 >> 3) * 64, n0 = (t6 & 7) * 64;
  const float* Wl = W + (size_t)l * HIDDEN * HIDDEN;
  unsigned short* Wtl = Wt + (size_t)l * HIDDEN * HIDDEN;
  int t = threadIdx.x;
#pragma unroll
  for (int r = 0; r < 4; ++r) {
    int row = (t >> 4) + r * 16;
    int col = (t & 15) * 4;
    float4 v = *(const float4*)(Wl + (size_t)(k0 + row) * HIDDEN + n0 + col);
    tile[col + 0][row] = f2bf(v.x);
    tile[col + 1][row] = f2bf(v.y);
    tile[col + 2][row] = f2bf(v.z);
    tile[col + 3][row] = f2bf(v.w);
  }
  __syncthreads();
#pragma unroll
  for (int r = 0; r < 4; ++r) {
    int row = (t >> 4) + r * 16;
    int col = (t & 15) * 4;
    ushort4 o;
    o.x = tile[row][col + 0]; o.y = tile[row][col + 1];
    o.z = tile[row][col + 2]; o.w = tile[row][col + 3];
    *(ushort4*)(Wtl + (size_t)(n0 + row) * HIDDEN + k0 + col) = o;
  }
}

// ---------------------------------------------------------------------------
// bf16 MFMA GEMM (unchanged from round 4): 128x128 tile, BK=32, 4 waves 2x2.
// ---------------------------------------------------------------------------
__global__ __launch_bounds__(256) void gemm_mfma_kernel(
    const unsigned short* __restrict__ A,
    const unsigned short* __restrict__ Wt,
    const float* __restrict__ bias,
    float* __restrict__ C) {
  __shared__ unsigned short As[128 * 40];
  __shared__ unsigned short Bs[128 * 40];
  int t = threadIdx.x;
  int n0 = blockIdx.x * 128;
  int m0 = blockIdx.y * 128;
  int w = t >> 6, lane = t & 63;
  int wr = w >> 1, wc = w & 1;
  int lm = lane & 15, q = lane >> 4;

  f32x4 acc[4][4];
#pragma unroll
  for (int i = 0; i < 4; ++i)
#pragma unroll
    for (int j = 0; j < 4; ++j) acc[i][j] = (f32x4){0.f, 0.f, 0.f, 0.f};

  int srow = t >> 2;
  int scol = (t & 3) * 8;

  for (int k0 = 0; k0 < HIDDEN; k0 += 32) {
    uint4 a0 = *(const uint4*)(A + (size_t)(m0 + srow) * HIDDEN + k0 + scol);
    uint4 a1 = *(const uint4*)(A + (size_t)(m0 + srow + 64) * HIDDEN + k0 + scol);
    uint4 b0 = *(const uint4*)(Wt + (size_t)(n0 + srow) * HIDDEN + k0 + scol);
    uint4 b1 = *(const uint4*)(Wt + (size_t)(n0 + srow + 64) * HIDDEN + k0 + scol);
    __syncthreads();
    *(uint4*)(As + srow * 40 + scol) = a0;
    *(uint4*)(As + (srow + 64) * 40 + scol) = a1;
    *(uint4*)(Bs + srow * 40 + scol) = b0;
    *(uint4*)(Bs + (srow + 64) * 40 + scol) = b1;
    __syncthreads();
    short8 af[4], bfr[4];
#pragma unroll
    for (int i = 0; i < 4; ++i)
      af[i] = *(const short8*)(As + (wr * 64 + i * 16 + lm) * 40 + q * 8);
#pragma unroll
    for (int j = 0; j < 4; ++j)
      bfr[j] = *(const short8*)(Bs + (wc * 64 + j * 16 + lm) * 40 + q * 8);
#pragma unroll
    for (int i = 0; i < 4; ++i)
#pragma unroll
      for (int j = 0; j < 4; ++j)
        acc[i][j] = __builtin_amdgcn_mfma_f32_16x16x32_bf16(af[i], bfr[j], acc[i][j], 0, 0, 0);
  }

#pragma unroll
  for (int i = 0; i < 4; ++i) {
    int row = m0 + wr * 64 + i * 16 + q * 4;
#pragma unroll
    for (int j = 0; j < 4; ++j) {
      int col = n0 + wc * 64 + j * 16 + lm;
      float bv = bias[col];
#pragma unroll
      for (int r = 0; r < 4; ++r)
        C[(size_t)(row + r) * HIDDEN + col] = acc[i][j][r] + bv;
    }
  }
}

// ---------------------------------------------------------------------------
// LayerNorm + ReLU + residual, sorted space. State carried in bf16 xs.
// final=0: xs[row] = bf16(result). final=1: out[perm(row)] = fp32 result.
// ---------------------------------------------------------------------------
__global__ __launch_bounds__(256) void ln_relu_res_kernel(
    const float* __restrict__ t, const float* __restrict__ g,
    const float* __restrict__ be, unsigned short* __restrict__ xs,
    float* __restrict__ out, const int* __restrict__ sorig,
    int N, int addres, int final_) {
  int row = (blockIdx.x << 2) + (threadIdx.x >> 6);
  int lane = threadIdx.x & 63;
  const float4* tr = (const float4*)(t + (size_t)row * HIDDEN);
  float4 v0 = tr[lane];
  float4 v1 = tr[lane + 64];
  float s = ((v0.x + v0.y) + (v0.z + v0.w)) + ((v1.x + v1.y) + (v1.z + v1.w));
  float ss = ((v0.x * v0.x + v0.y * v0.y) + (v0.z * v0.z + v0.w * v0.w)) +
             ((v1.x * v1.x + v1.y * v1.y) + (v1.z * v1.z + v1.w * v1.w));
#pragma unroll
  for (int o = 32; o > 0; o >>= 1) {
    s += __shfl_xor(s, o, 64);
    ss += __shfl_xor(ss, o, 64);
  }
  float mu = s * (1.0f / HIDDEN);
  float var = ss * (1.0f / HIDDEN) - mu * mu;
  float inv = rsqrtf(var + EPSV);
  float4 g0 = ((const float4*)g)[lane], g1 = ((const float4*)g)[lane + 64];
  float4 b0 = ((const float4*)be)[lane], b1 = ((const float4*)be)[lane + 64];
  float4 o0, o1;
  o0.x = fmaxf((v0.x - mu) * inv * g0.x + b0.x, 0.f);
  o0.y = fmaxf((v0.y - mu) * inv * g0.y + b0.y, 0.f);
  o0.z = fmaxf((v0.z - mu) * inv * g0.z + b0.z, 0.f);
  o0.w = fmaxf((v0.w - mu) * inv * g0.w + b0.w, 0.f);
  o1.x = fmaxf((v1.x - mu) * inv * g1.x + b1.x, 0.f);
  o1.y = fmaxf((v1.y - mu) * inv * g1.y + b1.y, 0.f);
  o1.z = fmaxf((v1.z - mu) * inv * g1.z + b1.z, 0.f);
  o1.w = fmaxf((v1.w - mu) * inv * g1.w + b1.w, 0.f);
  ushort4* xrow = (ushort4*)(xs + (size_t)row * HIDDEN);
  if (addres) {
    ushort4 r0 = xrow[lane], r1 = xrow[lane + 64];
    o0.x += bf2f(r0.x); o0.y += bf2f(r0.y); o0.z += bf2f(r0.z); o0.w += bf2f(r0.w);
    o1.x += bf2f(r1.x); o1.y += bf2f(r1.y); o1.z += bf2f(r1.z); o1.w += bf2f(r1.w);
  }
  if (final_) {
    int b = row / N;
    int dst = b * N + sorig[row];
    float4* orow = (float4*)(out + (size_t)dst * HIDDEN);
    orow[lane] = o0;
    orow[lane + 64] = o1;
  } else {
    ushort4 q0, q1;
    q0.x = f2bf(o0.x); q0.y = f2bf(o0.y); q0.z = f2bf(o0.z); q0.w = f2bf(o0.w);
    q1.x = f2bf(o1.x); q1.y = f2bf(o1.y); q1.z = f2bf(o1.z); q1.w = f2bf(o1.w);
    xrow[lane] = q0;
    xrow[lane + 64] = q1;
  }
}

// ---------------------------------------------------------------------------
extern "C" void kernel_launch(void* const* d_in, const int* in_sizes, int n_in,
                              void* d_out, int out_size, void* d_ws, size_t ws_size,
                              hipStream_t stream) {
  const float* nf = (const float*)d_in[0];
  const float2* coords = (const float2*)d_in[1];
  const float* Wall = (const float*)d_in[2];
  const float* ball = (const float*)d_in[3];
  const float* gall = (const float*)d_in[4];
  const float* beall = (const float*)d_in[5];
  float* out = (float*)d_out;

  int BN = in_sizes[0] / HIDDEN;  // 16384
  int N = 4096;
  int B = BN / N;

  char* ws = (char*)d_ws;
  size_t off = 0;
  auto alloc = [&](size_t bytes) -> void* {
    off = (off + 255) & ~(size_t)255;
    void* p = ws + off;
    off += bytes;
    return p;
  };
  int* knn_s = (int*)alloc((size_t)BN * KNN * sizeof(int));
  int* cnt = (int*)alloc((size_t)BN * sizeof(int));
  int* rev = (int*)alloc((size_t)BN * CAP * sizeof(int));
  unsigned short* aggb = (unsigned short*)alloc((size_t)BN * HIDDEN * sizeof(unsigned short));
  float* tmp = (float*)alloc((size_t)BN * HIDDEN * sizeof(float));
  unsigned short* Wt = (unsigned short*)alloc((size_t)NLAYERS * HIDDEN * HIDDEN * sizeof(unsigned short));
  unsigned short* xs = (unsigned short*)alloc((size_t)BN * HIDDEN * sizeof(unsigned short));
  int* cell_start = (int*)alloc((size_t)B * (NCELL + 1) * sizeof(int));
  float2* scoord = (float2*)alloc((size_t)BN * sizeof(float2));
  int* sorig = (int*)alloc((size_t)BN * sizeof(int));

  hipMemsetAsync(cnt, 0, (size_t)BN * sizeof(int), stream);
  grid_build_kernel<<<B, 1024, 0, stream>>>(coords, cell_start, scoord, sorig, N);
  knn_grid_kernel<<<(BN * 8 + 255) / 256, 256, 0, stream>>>(cell_start, scoord, sorig, knn_s, N, BN);
  rev_build_kernel<<<(BN * KNN) / 256, 256, 0, stream>>>(knn_s, cnt, rev, N, BN);
  wconv_kernel<<<NLAYERS * 64, 256, 0, stream>>>(Wall, Wt);
  x2bf_perm_kernel<<<BN, 128, 0, stream>>>(nf, sorig, xs, N);

  for (int l = 0; l < NLAYERS; ++l) {
    agg_kernel<<<BN, 128, 0, stream>>>(xs, knn_s, cnt, rev, aggb, N);
    gemm_mfma_kernel<<<dim3(HIDDEN / 128, BN / 128), 256, 0, stream>>>(
        aggb, Wt + (size_t)l * HIDDEN * HIDDEN, ball + (size_t)l * HIDDEN, tmp);
    ln_relu_res_kernel<<<BN / 4, 256, 0, stream>>>(
        tmp, gall + (size_t)l * HIDDEN, beall + (size_t)l * HIDDEN,
        xs, out, sorig, N, l > 0, l == NLAYERS - 1);
  }
}